// Round 13
// baseline (247.078 us; speedup 1.0000x reference)
//
#include <hip/hip_runtime.h>
#include <math.h>

// Problem constants
#define BB 32
#define CC 122
#define TT 500
#define SS 13
#define WID 80
#define EMB 8
#define PROJ 1024
#define HID 768
#define TP 96          // pooled time length
#define EPSF 1e-5f
#define KP 9760        // conv2 flat K' = 122*80
#define KBN 305        // KP/32 kb-groups
#define KSPLIT 16
#define NTAIL 64

typedef float f32x4 __attribute__((ext_vector_type(4)));
typedef __bf16 bf16x8 __attribute__((ext_vector_type(8)));
typedef unsigned short u16x8 __attribute__((ext_vector_type(8)));
union BF8 { u16x8 u; bf16x8 b; };

// float -> bf16 bits, round-to-nearest-even
__device__ __forceinline__ unsigned short f2bf(float f) {
    union { float f; unsigned u; } v; v.f = f;
    unsigned r = v.u + 0x7FFFu + ((v.u >> 16) & 1u);
    return (unsigned short)(r >> 16);
}

// cheap ELU: hw v_exp; |err| ~1e-7, invisible vs bf16 noise
__device__ __forceinline__ float eluf(float x) {
    return x > 0.f ? x : __expf(x) - 1.f;
}

// ---------------- workspace layout (float offsets) ----------------
// p2 is the MFMA-fragment-ordered pooled tensor:
//   P2[b][kb][tt][l][8] : short index q=l*8+j holds p(t = tt*16 + (l&15),
//   k = kb*32 + (l>>4)*8 + j) — exactly the HW B-fragment for lane l.
#define OFF_E    ((size_t)0)            // oute (B,C,T) f32        1,952,000
#define OFF_XB   ((size_t)1952000)      // x_bf (B,128,512) bf16
#define OFF_WB   ((size_t)3000576)      // W_bf (S,512,512) bf16
#define OFF_W2P  ((size_t)4704512)      // w2p (80,9760) bf16
#define OFF_P    ((size_t)5094912)      // p2 (B,305,6,512) bf16 = 29,982,720 shorts
#define OFF_PART ((size_t)20086272)     // (KS,B,WID,TP) f32
#define OFF_Z    ((size_t)24018432)     // z_bf (B,HID) bf16
#define OFF_G    ((size_t)24063488)     // g_bf (B,PROJ) bf16
#define OFF_Y    ((size_t)24079872)     // y (B,PROJ) f32
#define OFF_W1B  ((size_t)24112640)     // w1b (PROJ,HID) bf16
#define OFF_W2B  ((size_t)24505856)     // w2b (PROJ,PROJ) bf16
#define OFF_WCB  ((size_t)25030144)     // wcb (80,32) bf16
#define OFF_B1F  ((size_t)25031424)     // (WID)
#define OFF_SC2  ((size_t)25031504)     // (WID)
#define OFF_SH2  ((size_t)25031584)     // (WID)
#define OFF_CNT  ((size_t)25031664)     // u32 bar[8] for tail grid barriers

// pack region sizes (elements)
#define NPK_X  (2097152)   // 32*128*512
#define NPK_W  (3407872)   // 13*512*512
#define NPK_W2 (780800)    // 80*9760
#define NPK_M1 (786432)    // 1024*768
#define NPK_M2 (1048576)   // 1024*1024
#define NPK_TOT (NPK_X + NPK_W + NPK_W2 + NPK_M1 + NPK_M2)

// ---------------- pack (bf16 staging) + prep + bar zero (block 0) ----------------
__global__ __launch_bounds__(256) void k_pack(const float* __restrict__ x,
                                              const float* __restrict__ W_sub,
                                              const float* __restrict__ conv2_w,
                                              const float* __restrict__ mlp1_w,
                                              const float* __restrict__ mlp2_w,
                                              const float* __restrict__ conv1_w, const float* __restrict__ conv1_b,
                                              const float* __restrict__ g1, const float* __restrict__ b1,
                                              const float* __restrict__ m1, const float* __restrict__ v1,
                                              const float* __restrict__ conv2_b, const float* __restrict__ g2,
                                              const float* __restrict__ b2, const float* __restrict__ m2,
                                              const float* __restrict__ v2,
                                              unsigned short* __restrict__ xb,
                                              unsigned short* __restrict__ wb,
                                              unsigned short* __restrict__ w2p,
                                              unsigned short* __restrict__ w1b,
                                              unsigned short* __restrict__ w2b,
                                              unsigned short* __restrict__ wcb, float* __restrict__ bias1f,
                                              float* __restrict__ scale2, float* __restrict__ shift2f,
                                              unsigned* __restrict__ bar) {
    if (blockIdx.x == 0) {
        int o = threadIdx.x;
        if (o < 8) bar[o] = 0u;          // zero tail barriers EVERY launch (ws poisoned)
        if (o < WID) {
            float s1 = g1[o] * rsqrtf(v1[o] + EPSF);
            float sh1 = b1[o] - m1[o] * s1;
            #pragma unroll
            for (int d = 0; d < 21; d++) {
                int klo = d - 16; if (klo < 0) klo = 0;
                int khi = d;      if (khi > 4) khi = 4;
                float acc = 0.f;
                for (int k = klo; k <= khi; k++) acc += conv1_w[o*5 + k];
                wcb[o*32 + d] = f2bf(acc * s1 * (1.f/17.f));
            }
            #pragma unroll
            for (int d = 21; d < 32; d++) wcb[o*32 + d] = 0;
            bias1f[o] = conv1_b[o] * s1 + sh1;
            float s2 = g2[o] * rsqrtf(v2[o] + EPSF);
            scale2[o] = s2;
            shift2f[o] = conv2_b[o] * s2 + (b2[o] - m2[o] * s2);
        }
    }
    size_t idx = (size_t)blockIdx.x * 256 + threadIdx.x;
    if (idx >= (size_t)NPK_TOT) return;
    if (idx < NPK_X) {
        int s = idx & 511, c = (idx >> 9) & 127, b = idx >> 16;
        float v = (c < CC && s < TT) ? x[((size_t)b * CC + c) * TT + s] : 0.f;
        xb[idx] = f2bf(v);
    } else if (idx < NPK_X + NPK_W) {
        size_t j = idx - NPK_X;
        int s = j & 511, t = (j >> 9) & 511, sub = j >> 18;
        float v = (t < TT && s < TT) ? W_sub[((size_t)sub * TT + t) * TT + s] : 0.f;
        wb[j] = f2bf(v);
    } else if (idx < NPK_X + NPK_W + NPK_W2) {
        size_t j = idx - NPK_X - NPK_W;
        int o = (int)(j / KP);
        int k = (int)(j % KP);
        int c = k / WID, op = k % WID;
        w2p[j] = f2bf(conv2_w[((size_t)(o * WID + op)) * CC + c]);
    } else if (idx < NPK_X + NPK_W + NPK_W2 + NPK_M1) {
        size_t j = idx - NPK_X - NPK_W - NPK_W2;
        w1b[j] = f2bf(mlp1_w[j]);
    } else {
        size_t j = idx - NPK_X - NPK_W - NPK_W2 - NPK_M1;
        w2b[j] = f2bf(mlp2_w[j]);
    }
}

// ---------------- subject einsum via MFMA bf16 ----------------
__global__ __launch_bounds__(256) void k_einsum(const unsigned short* __restrict__ xb,
                                                const unsigned short* __restrict__ wb,
                                                const int* __restrict__ sid,
                                                const float* __restrict__ b_sub,
                                                float* __restrict__ oute) {
    int t0 = blockIdx.x * 64, b = blockIdx.y;
    int s = sid[b];
    int tid = threadIdx.x, w = tid >> 6, lr = tid & 15, lg = (tid >> 4) & 3;
    const unsigned short* A0 = xb + ((size_t)(b * 128 + w * 32 + lr)) * 512 + 8 * lg;
    const unsigned short* Bb = wb + (size_t)s * 262144 + 8 * lg;
    f32x4 acc[2][4] = {};
    for (int kb = 0; kb < 512; kb += 32) {
        BF8 a0, a1;
        a0.u = *(const u16x8*)(A0 + kb);
        a1.u = *(const u16x8*)(A0 + 16 * 512 + kb);
        #pragma unroll
        for (int nt = 0; nt < 4; nt++) {
            BF8 bf; bf.u = *(const u16x8*)(Bb + (size_t)(t0 + nt * 16 + lr) * 512 + kb);
            acc[0][nt] = __builtin_amdgcn_mfma_f32_16x16x32_bf16(a0.b, bf.b, acc[0][nt], 0, 0, 0);
            acc[1][nt] = __builtin_amdgcn_mfma_f32_16x16x32_bf16(a1.b, bf.b, acc[1][nt], 0, 0, 0);
        }
    }
    const float* bg = b_sub + (size_t)s * TT;
    #pragma unroll
    for (int nt = 0; nt < 4; nt++) {
        int t = t0 + nt * 16 + lr;
        if (t < TT) {
            float bias = bg[t];
            #pragma unroll
            for (int mt = 0; mt < 2; mt++) {
                int crow = w * 32 + mt * 16 + 4 * lg;
                #pragma unroll
                for (int r = 0; r < 4; r++) {
                    int c = crow + r;
                    if (c < CC) oute[((size_t)b * CC + c) * TT + t] = acc[mt][nt][r] + bias;
                }
            }
        }
    }
}

// ---------------- FIR via MFMA -> P2 fragment layout (LDS-staged, coalesced out) ----
__global__ __launch_bounds__(256) void k_fir2(const float* __restrict__ oute,
                                              const unsigned short* __restrict__ wcb,
                                              const float* __restrict__ b1f,
                                              unsigned short* __restrict__ p2) {
    __shared__ float e2[2][512];
    __shared__ unsigned short pt[96][164];
    int cp = blockIdx.x, b = blockIdx.y;
    int tid = threadIdx.x;
    int w = tid >> 6, lr = tid & 15, lg = (tid >> 4) & 3;
    if (tid < 250) {
        int cc = tid / 125, i = tid % 125;
        ((float4*)e2[cc])[i] = ((const float4*)(oute + ((size_t)b * CC + cp * 2 + cc) * TT))[i];
    }
    if (tid >= 232) {
        int j = tid - 232; int cc = j / 12, i = 500 + (j % 12);
        e2[cc][i] = 0.f;
    }
    BF8 af[5]; float4 bf4[5];
    #pragma unroll
    for (int ot = 0; ot < 5; ot++) {
        af[ot].u = *(const u16x8*)(wcb + (ot * 16 + lr) * 32 + 8 * lg);
        bf4[ot] = *(const float4*)(b1f + ot * 16 + 4 * lg);
    }
    __syncthreads();
    #pragma unroll
    for (int ui = 0; ui < 3; ui++) {
        int u = w + 4 * ui;
        int cc = u / 6, tt = u % 6;
        int t = tt * 16 + lr;
        const float* ew = e2[cc] + 5 * t + 8 * lg;
        BF8 bfr;
        #pragma unroll
        for (int j = 0; j < 8; j++) bfr.u[j] = f2bf(ew[j]);
        f32x4 acc[5] = {};
        #pragma unroll
        for (int ot = 0; ot < 5; ot++)
            acc[ot] = __builtin_amdgcn_mfma_f32_16x16x32_bf16(af[ot].b, bfr.b, acc[ot], 0, 0, 0);
        #pragma unroll
        for (int ot = 0; ot < 5; ot++) {
            union { unsigned short s[4]; uint2 v; } pk;
            #pragma unroll
            for (int r = 0; r < 4; r++) pk.s[r] = f2bf(eluf(acc[ot][r] + bf4[ot][r]));
            *(uint2*)&pt[t][cc * 80 + ot * 16 + 4 * lg] = pk.v;
        }
    }
    __syncthreads();
    const size_t base = ((size_t)b * KBN + 5 * (size_t)cp) * 3072;
    int q = 2 * tid;
    int l = q >> 3, jj = q & 7;
    int prow_lo = l & 15;
    int pcol_off = ((l >> 4) << 3) + jj;
    #pragma unroll
    for (int r = 0; r < 30; r++) {
        int kbl = r / 6, tt2 = r % 6;
        unsigned v = *(const unsigned*)&pt[tt2 * 16 + prow_lo][kbl * 32 + pcol_off];
        *(unsigned*)(p2 + base + (size_t)(kbl * 6 + tt2) * 512 + q) = v;
    }
}

// ---------------- conv2 pure MFMA GEMM over P2 (coalesced B) ----------------
__global__ __launch_bounds__(384) void k_conv2(const unsigned short* __restrict__ p2,
                                               const unsigned short* __restrict__ w2p,
                                               float* __restrict__ part) {
    int chunk = blockIdx.x, b = blockIdx.y;
    int tid = threadIdx.x, w = tid >> 6, l = tid & 63, lr = l & 15, lg = l >> 4;
    int kb0 = (chunk * KBN) / KSPLIT;
    int kb1 = ((chunk + 1) * KBN) / KSPLIT;
    const unsigned short* Bp = p2 + (size_t)b * KBN * 3072 + (size_t)w * 512 + (size_t)l * 8;
    const unsigned short* Arow = w2p + (size_t)lr * KP + 8 * lg;
    f32x4 acc[5] = {};
    for (int kb = kb0; kb < kb1; kb++) {
        BF8 bf; bf.u = *(const u16x8*)(Bp + (size_t)kb * 3072);
        int ko = kb * 32;
        #pragma unroll
        for (int mt = 0; mt < 5; mt++) {
            BF8 af; af.u = *(const u16x8*)(Arow + (size_t)mt * 16 * KP + ko);
            acc[mt] = __builtin_amdgcn_mfma_f32_16x16x32_bf16(af.b, bf.b, acc[mt], 0, 0, 0);
        }
    }
    float* pp = part + ((size_t)(chunk * BB + b) * WID) * TP;
    int t = w * 16 + lr;
    #pragma unroll
    for (int mt = 0; mt < 5; mt++) {
        int ob = mt * 16 + 4 * lg;
        #pragma unroll
        for (int r = 0; r < 4; r++)
            pp[(size_t)(ob + r) * TP + t] = acc[mt][r];
    }
}

// ---------------- grid barrier over NTAIL blocks (device scope; proven in round 8) ----
__device__ __forceinline__ void gbarrier(unsigned* ctr) {
    __threadfence();
    __syncthreads();
    if (threadIdx.x == 0) {
        atomicAdd(ctr, 1u);
        while (atomicAdd(ctr, 0u) < NTAIL) {}
    }
    __syncthreads();
    __threadfence();
}

// ---------------- fused tail: redproj -> mlp1+gelu -> mlp2+res -> LN ----------------
// 64 blocks x 256 thr. Phase 0 on blocks 0..31 (per-b); phases 1/2 on all 64
// (16 cols each, z1 in kh==0 regs); phase 3 on blocks 0..31. 3 grid barriers.
__global__ __launch_bounds__(256) void k_tail(const float* __restrict__ part,
                                              const float* __restrict__ scale2,
                                              const float* __restrict__ shift2f,
                                              const float* __restrict__ pw,
                                              const float* __restrict__ pb,
                                              const unsigned short* __restrict__ w1b,
                                              const float* __restrict__ b1m,
                                              const unsigned short* __restrict__ w2b,
                                              const float* __restrict__ b2m,
                                              const float* __restrict__ lg_,
                                              const float* __restrict__ lb_,
                                              unsigned short* __restrict__ zbf,
                                              unsigned short* __restrict__ gbf,
                                              float* __restrict__ y,
                                              float* __restrict__ out,
                                              unsigned* __restrict__ bar) {
    __shared__ float ly[WID * TP];   // 30 KB (phase 0 only)
    __shared__ float lw[EMB * WID];
    __shared__ float accb[2][64][4];
    int tid = threadIdx.x, w = tid >> 6, l = tid & 63, lr = l & 15, lg = l >> 4;
    int mt = w & 1, kh = w >> 1;
    float z1r[4];

    // ---- phase 0: split-K reduce + bn2 + elu + proj -> zbf (blocks 0..31)
    if (blockIdx.x < BB) {
        int b = blockIdx.x;
        for (int i = tid; i < EMB * WID; i += 256) lw[i] = pw[i];
        for (int i = tid; i < WID * TP; i += 256) {
            float acc = 0.f;
            #pragma unroll
            for (int ks = 0; ks < KSPLIT; ks++)
                acc += part[(size_t)(ks * BB + b) * (WID * TP) + i];
            int o = i / TP;
            ly[i] = eluf(acc * scale2[o] + shift2f[o]);
        }
        __syncthreads();
        #pragma unroll
        for (int rep = 0; rep < 3; rep++) {
            int j = tid + 256 * rep;
            int e = j & 7, t = j >> 3;
            float acc = pb[e];
            #pragma unroll 10
            for (int o = 0; o < WID; o++) acc = fmaf(ly[o * TP + t], lw[e * WID + o], acc);
            zbf[(size_t)b * HID + j] = f2bf(acc);
        }
    }
    gbarrier(bar + 0);

    // ---- phase 1: z1 cols = blockIdx*16+lr; gbf = gelu(z1)
    {
        int pcol = blockIdx.x * 16 + lr;
        const unsigned short* wr = w1b + (size_t)pcol * HID + kh * 384 + 8 * lg;
        const unsigned short* za = zbf + (size_t)(mt * 16 + lr) * HID + kh * 384 + 8 * lg;
        f32x4 acc = {};
        for (int kb = 0; kb < 384; kb += 32) {
            BF8 bf; bf.u = *(const u16x8*)(wr + kb);
            BF8 a;  a.u  = *(const u16x8*)(za + kb);
            acc = __builtin_amdgcn_mfma_f32_16x16x32_bf16(a.b, bf.b, acc, 0, 0, 0);
        }
        if (kh == 1) {
            #pragma unroll
            for (int r = 0; r < 4; r++) accb[mt][l][r] = acc[r];
        }
        __syncthreads();
        if (kh == 0) {
            float bs = b1m[pcol];
            #pragma unroll
            for (int r = 0; r < 4; r++) {
                int row = mt * 16 + 4 * lg + r;
                float v = acc[r] + accb[mt][l][r] + bs;
                z1r[r] = v;
                gbf[(size_t)row * PROJ + pcol] = f2bf(0.5f * v * (1.f + erff(v * 0.70710678118654752f)));
            }
        }
    }
    gbarrier(bar + 1);

    // ---- phase 2: y = z1 + Gbf @ W2b^T + b2 (same cols, z1 in regs)
    {
        int q = blockIdx.x * 16 + lr;
        const unsigned short* wr = w2b + (size_t)q * PROJ + kh * 512 + 8 * lg;
        const unsigned short* ga = gbf + (size_t)(mt * 16 + lr) * PROJ + kh * 512 + 8 * lg;
        f32x4 acc = {};
        for (int kb = 0; kb < 512; kb += 32) {
            BF8 bf; bf.u = *(const u16x8*)(wr + kb);
            BF8 a;  a.u  = *(const u16x8*)(ga + kb);
            acc = __builtin_amdgcn_mfma_f32_16x16x32_bf16(a.b, bf.b, acc, 0, 0, 0);
        }
        if (kh == 1) {
            #pragma unroll
            for (int r = 0; r < 4; r++) accb[mt][l][r] = acc[r];
        }
        __syncthreads();
        if (kh == 0) {
            float bs = b2m[q];
            #pragma unroll
            for (int r = 0; r < 4; r++) {
                int row = mt * 16 + 4 * lg + r;
                y[(size_t)row * PROJ + q] = acc[r] + accb[mt][l][r] + bs + z1r[r];
            }
        }
    }
    gbarrier(bar + 2);

    // ---- phase 3: LayerNorm rows 0..31 on blocks 0..31
    if (blockIdx.x < BB) {
        int b = blockIdx.x;
        const float4* yr = (const float4*)(y + (size_t)b * PROJ);
        float4 v = yr[tid];
        float s  = v.x + v.y + v.z + v.w;
        float sq = v.x*v.x + v.y*v.y + v.z*v.z + v.w*v.w;
        #pragma unroll
        for (int off = 32; off > 0; off >>= 1) {
            s  += __shfl_down(s, off);
            sq += __shfl_down(sq, off);
        }
        __shared__ float ss[4], ssq[4];
        __shared__ float smu, sinv;
        int wv = tid >> 6, lane = tid & 63;
        if (lane == 0) { ss[wv] = s; ssq[wv] = sq; }
        __syncthreads();
        if (tid == 0) {
            float Sm = ss[0] + ss[1] + ss[2] + ss[3];
            float Sq = ssq[0] + ssq[1] + ssq[2] + ssq[3];
            float mu = Sm * (1.f / PROJ);
            float var = Sq * (1.f / PROJ) - mu * mu;
            smu = mu;
            sinv = rsqrtf(var + EPSF);
        }
        __syncthreads();
        float mu = smu, inv = sinv;
        float4 g4 = ((const float4*)lg_)[tid];
        float4 b4 = ((const float4*)lb_)[tid];
        float4 o4;
        o4.x = (v.x - mu) * inv * g4.x + b4.x;
        o4.y = (v.y - mu) * inv * g4.y + b4.y;
        o4.z = (v.z - mu) * inv * g4.z + b4.z;
        o4.w = (v.w - mu) * inv * g4.w + b4.w;
        ((float4*)(out + (size_t)b * PROJ))[tid] = o4;
    }
}

extern "C" void kernel_launch(void* const* d_in, const int* in_sizes, int n_in,
                              void* d_out, int out_size, void* d_ws, size_t ws_size,
                              hipStream_t stream) {
    const float* x        = (const float*)d_in[0];
    const int*   sid      = (const int*)  d_in[1];
    const float* W_sub    = (const float*)d_in[2];
    const float* b_sub    = (const float*)d_in[3];
    const float* conv1_w  = (const float*)d_in[4];
    const float* conv1_b  = (const float*)d_in[5];
    const float* bn1_g    = (const float*)d_in[6];
    const float* bn1_b    = (const float*)d_in[7];
    const float* bn1_m    = (const float*)d_in[8];
    const float* bn1_v    = (const float*)d_in[9];
    const float* conv2_w  = (const float*)d_in[10];
    const float* conv2_b  = (const float*)d_in[11];
    const float* bn2_g    = (const float*)d_in[12];
    const float* bn2_b    = (const float*)d_in[13];
    const float* bn2_m    = (const float*)d_in[14];
    const float* bn2_v    = (const float*)d_in[15];
    const float* proj_w   = (const float*)d_in[16];
    const float* proj_b   = (const float*)d_in[17];
    const float* mlp1_w   = (const float*)d_in[18];
    const float* mlp1_b   = (const float*)d_in[19];
    const float* mlp2_w   = (const float*)d_in[20];
    const float* mlp2_b   = (const float*)d_in[21];
    const float* ln_g     = (const float*)d_in[22];
    const float* ln_b     = (const float*)d_in[23];
    float* out = (float*)d_out;
    float* ws  = (float*)d_ws;

    float* ws_e    = ws + OFF_E;
    unsigned short* ws_xb  = (unsigned short*)(ws + OFF_XB);
    unsigned short* ws_wb  = (unsigned short*)(ws + OFF_WB);
    unsigned short* ws_w2p = (unsigned short*)(ws + OFF_W2P);
    unsigned short* ws_p2  = (unsigned short*)(ws + OFF_P);
    float* ws_part = ws + OFF_PART;
    unsigned short* ws_zbf = (unsigned short*)(ws + OFF_Z);
    unsigned short* ws_gbf = (unsigned short*)(ws + OFF_G);
    float* ws_y    = ws + OFF_Y;
    unsigned short* ws_w1b = (unsigned short*)(ws + OFF_W1B);
    unsigned short* ws_w2b = (unsigned short*)(ws + OFF_W2B);
    unsigned short* ws_wcb = (unsigned short*)(ws + OFF_WCB);
    float* ws_b1f  = ws + OFF_B1F;
    float* ws_sc2  = ws + OFF_SC2;
    float* ws_sh2  = ws + OFF_SH2;
    unsigned* ws_bar = (unsigned*)(ws + OFF_CNT);

    hipLaunchKernelGGL(k_pack, dim3((NPK_TOT + 255) / 256), dim3(256), 0, stream,
                       x, W_sub, conv2_w, mlp1_w, mlp2_w,
                       conv1_w, conv1_b, bn1_g, bn1_b, bn1_m, bn1_v,
                       conv2_b, bn2_g, bn2_b, bn2_m, bn2_v,
                       ws_xb, ws_wb, ws_w2p, ws_w1b, ws_w2b,
                       ws_wcb, ws_b1f, ws_sc2, ws_sh2, ws_bar);

    hipLaunchKernelGGL(k_einsum, dim3(8, BB), dim3(256), 0, stream,
                       ws_xb, ws_wb, sid, b_sub, ws_e);

    hipLaunchKernelGGL(k_fir2, dim3(CC / 2, BB), dim3(256), 0, stream,
                       ws_e, ws_wcb, ws_b1f, ws_p2);

    hipLaunchKernelGGL(k_conv2, dim3(KSPLIT, BB), dim3(384), 0, stream,
                       ws_p2, ws_w2p, ws_part);

    hipLaunchKernelGGL(k_tail, dim3(NTAIL), dim3(256), 0, stream,
                       ws_part, ws_sc2, ws_sh2, proj_w, proj_b,
                       ws_w1b, mlp1_b, ws_w2b, mlp2_b, ln_g, ln_b,
                       ws_zbf, ws_gbf, ws_y, out, ws_bar);
}

// Round 14
// 214.339 us; speedup vs baseline: 1.1527x; 1.1527x over previous
//
#include <hip/hip_runtime.h>
#include <math.h>

// Problem constants
#define BB 32
#define CC 122
#define TT 500
#define SS 13
#define WID 80
#define EMB 8
#define PROJ 1024
#define HID 768
#define TP 96          // pooled time length
#define EPSF 1e-5f
#define KP 9760        // conv2 flat K' = 122*80
#define KBN 305        // KP/32 kb-groups
#define KSPLIT 16

typedef float f32x4 __attribute__((ext_vector_type(4)));
typedef __bf16 bf16x8 __attribute__((ext_vector_type(8)));
typedef unsigned short u16x8 __attribute__((ext_vector_type(8)));
union BF8 { u16x8 u; bf16x8 b; };

// float -> bf16 bits, round-to-nearest-even
__device__ __forceinline__ unsigned short f2bf(float f) {
    union { float f; unsigned u; } v; v.f = f;
    unsigned r = v.u + 0x7FFFu + ((v.u >> 16) & 1u);
    return (unsigned short)(r >> 16);
}

// cheap ELU: hw v_exp; |err| ~1e-7, invisible vs bf16 noise
__device__ __forceinline__ float eluf(float x) {
    return x > 0.f ? x : __expf(x) - 1.f;
}

// ---------------- workspace layout (float offsets) ----------------
// p2 is the MFMA-fragment-ordered pooled tensor:
//   P2[b][kb][tt][l][8] : short index q=l*8+j holds p(t = tt*16 + (l&15),
//   k = kb*32 + (l>>4)*8 + j) — exactly the HW B-fragment for lane l.
#define OFF_E    ((size_t)0)            // oute (B,C,T) f32        1,952,000
#define OFF_XB   ((size_t)1952000)      // x_bf (B,128,512) bf16
#define OFF_WB   ((size_t)3000576)      // W_bf (S,512,512) bf16
#define OFF_W2P  ((size_t)4704512)      // w2p (80,9760) bf16
#define OFF_P    ((size_t)5094912)      // p2 (B,305,6,512) bf16 = 29,982,720 shorts
#define OFF_PART ((size_t)20086272)     // (KS,B,WID,TP) f32
#define OFF_Z    ((size_t)24018432)     // z_bf (B,HID) bf16
#define OFF_Z1   ((size_t)24030720)     // z1 (B,PROJ) f32
#define OFF_G    ((size_t)24063488)     // g_bf (B,PROJ) bf16
#define OFF_Y    ((size_t)24079872)     // y (B,PROJ) f32
#define OFF_W1B  ((size_t)24112640)     // w1b (PROJ,HID) bf16
#define OFF_W2B  ((size_t)24505856)     // w2b (PROJ,PROJ) bf16
#define OFF_WCB  ((size_t)25030144)     // wcb (80,32) bf16
#define OFF_B1F  ((size_t)25031424)     // (WID)
#define OFF_SC2  ((size_t)25031504)     // (WID)
#define OFF_SH2  ((size_t)25031584)     // (WID)

// pack region sizes (elements)
#define NPK_X  (2097152)   // 32*128*512
#define NPK_W  (3407872)   // 13*512*512
#define NPK_W2 (780800)    // 80*9760
#define NPK_M1 (786432)    // 1024*768
#define NPK_M2 (1048576)   // 1024*1024
#define NPK_TOT (NPK_X + NPK_W + NPK_W2 + NPK_M1 + NPK_M2)

// ---------------- pack (bf16 staging) + prep (block 0) ----------------
__global__ __launch_bounds__(256) void k_pack(const float* __restrict__ x,
                                              const float* __restrict__ W_sub,
                                              const float* __restrict__ conv2_w,
                                              const float* __restrict__ mlp1_w,
                                              const float* __restrict__ mlp2_w,
                                              const float* __restrict__ conv1_w, const float* __restrict__ conv1_b,
                                              const float* __restrict__ g1, const float* __restrict__ b1,
                                              const float* __restrict__ m1, const float* __restrict__ v1,
                                              const float* __restrict__ conv2_b, const float* __restrict__ g2,
                                              const float* __restrict__ b2, const float* __restrict__ m2,
                                              const float* __restrict__ v2,
                                              unsigned short* __restrict__ xb,
                                              unsigned short* __restrict__ wb,
                                              unsigned short* __restrict__ w2p,
                                              unsigned short* __restrict__ w1b,
                                              unsigned short* __restrict__ w2b,
                                              unsigned short* __restrict__ wcb, float* __restrict__ bias1f,
                                              float* __restrict__ scale2, float* __restrict__ shift2f) {
    if (blockIdx.x == 0) {
        int o = threadIdx.x;
        if (o < WID) {
            float s1 = g1[o] * rsqrtf(v1[o] + EPSF);
            float sh1 = b1[o] - m1[o] * s1;
            #pragma unroll
            for (int d = 0; d < 21; d++) {
                int klo = d - 16; if (klo < 0) klo = 0;
                int khi = d;      if (khi > 4) khi = 4;
                float acc = 0.f;
                for (int k = klo; k <= khi; k++) acc += conv1_w[o*5 + k];
                wcb[o*32 + d] = f2bf(acc * s1 * (1.f/17.f));
            }
            #pragma unroll
            for (int d = 21; d < 32; d++) wcb[o*32 + d] = 0;
            bias1f[o] = conv1_b[o] * s1 + sh1;
            float s2 = g2[o] * rsqrtf(v2[o] + EPSF);
            scale2[o] = s2;
            shift2f[o] = conv2_b[o] * s2 + (b2[o] - m2[o] * s2);
        }
    }
    size_t idx = (size_t)blockIdx.x * 256 + threadIdx.x;
    if (idx >= (size_t)NPK_TOT) return;
    if (idx < NPK_X) {
        int s = idx & 511, c = (idx >> 9) & 127, b = idx >> 16;
        float v = (c < CC && s < TT) ? x[((size_t)b * CC + c) * TT + s] : 0.f;
        xb[idx] = f2bf(v);
    } else if (idx < NPK_X + NPK_W) {
        size_t j = idx - NPK_X;
        int s = j & 511, t = (j >> 9) & 511, sub = j >> 18;
        float v = (t < TT && s < TT) ? W_sub[((size_t)sub * TT + t) * TT + s] : 0.f;
        wb[j] = f2bf(v);
    } else if (idx < NPK_X + NPK_W + NPK_W2) {
        // coalesced READ of conv2_w (j enumerates (o,op,c) with c fastest =
        // conv2_w's native order); scattered 2B write absorbed by L2 write-back.
        size_t j = idx - NPK_X - NPK_W;
        int o  = (int)(j / (WID * CC));
        int r  = (int)(j % (WID * CC));
        int op = r / CC, c = r % CC;
        w2p[(size_t)o * KP + (size_t)c * WID + op] = f2bf(conv2_w[j]);
    } else if (idx < NPK_X + NPK_W + NPK_W2 + NPK_M1) {
        size_t j = idx - NPK_X - NPK_W - NPK_W2;
        w1b[j] = f2bf(mlp1_w[j]);
    } else {
        size_t j = idx - NPK_X - NPK_W - NPK_W2 - NPK_M1;
        w2b[j] = f2bf(mlp2_w[j]);
    }
}

// ---------------- subject einsum via MFMA bf16 ----------------
__global__ __launch_bounds__(256) void k_einsum(const unsigned short* __restrict__ xb,
                                                const unsigned short* __restrict__ wb,
                                                const int* __restrict__ sid,
                                                const float* __restrict__ b_sub,
                                                float* __restrict__ oute) {
    int t0 = blockIdx.x * 64, b = blockIdx.y;
    int s = sid[b];
    int tid = threadIdx.x, w = tid >> 6, lr = tid & 15, lg = (tid >> 4) & 3;
    const unsigned short* A0 = xb + ((size_t)(b * 128 + w * 32 + lr)) * 512 + 8 * lg;
    const unsigned short* Bb = wb + (size_t)s * 262144 + 8 * lg;
    f32x4 acc[2][4] = {};
    for (int kb = 0; kb < 512; kb += 32) {
        BF8 a0, a1;
        a0.u = *(const u16x8*)(A0 + kb);
        a1.u = *(const u16x8*)(A0 + 16 * 512 + kb);
        #pragma unroll
        for (int nt = 0; nt < 4; nt++) {
            BF8 bf; bf.u = *(const u16x8*)(Bb + (size_t)(t0 + nt * 16 + lr) * 512 + kb);
            acc[0][nt] = __builtin_amdgcn_mfma_f32_16x16x32_bf16(a0.b, bf.b, acc[0][nt], 0, 0, 0);
            acc[1][nt] = __builtin_amdgcn_mfma_f32_16x16x32_bf16(a1.b, bf.b, acc[1][nt], 0, 0, 0);
        }
    }
    const float* bg = b_sub + (size_t)s * TT;
    #pragma unroll
    for (int nt = 0; nt < 4; nt++) {
        int t = t0 + nt * 16 + lr;
        if (t < TT) {
            float bias = bg[t];
            #pragma unroll
            for (int mt = 0; mt < 2; mt++) {
                int crow = w * 32 + mt * 16 + 4 * lg;
                #pragma unroll
                for (int r = 0; r < 4; r++) {
                    int c = crow + r;
                    if (c < CC) oute[((size_t)b * CC + c) * TT + t] = acc[mt][nt][r] + bias;
                }
            }
        }
    }
}

// ---------------- FIR via MFMA -> P2 fragment layout (LDS-staged, coalesced out) ----
__global__ __launch_bounds__(256) void k_fir2(const float* __restrict__ oute,
                                              const unsigned short* __restrict__ wcb,
                                              const float* __restrict__ b1f,
                                              unsigned short* __restrict__ p2) {
    __shared__ float e2[2][512];
    __shared__ unsigned short pt[96][164];
    int cp = blockIdx.x, b = blockIdx.y;
    int tid = threadIdx.x;
    int w = tid >> 6, lr = tid & 15, lg = (tid >> 4) & 3;
    if (tid < 250) {
        int cc = tid / 125, i = tid % 125;
        ((float4*)e2[cc])[i] = ((const float4*)(oute + ((size_t)b * CC + cp * 2 + cc) * TT))[i];
    }
    if (tid >= 232) {
        int j = tid - 232; int cc = j / 12, i = 500 + (j % 12);
        e2[cc][i] = 0.f;
    }
    BF8 af[5]; float4 bf4[5];
    #pragma unroll
    for (int ot = 0; ot < 5; ot++) {
        af[ot].u = *(const u16x8*)(wcb + (ot * 16 + lr) * 32 + 8 * lg);
        bf4[ot] = *(const float4*)(b1f + ot * 16 + 4 * lg);
    }
    __syncthreads();
    #pragma unroll
    for (int ui = 0; ui < 3; ui++) {
        int u = w + 4 * ui;
        int cc = u / 6, tt = u % 6;
        int t = tt * 16 + lr;
        const float* ew = e2[cc] + 5 * t + 8 * lg;
        BF8 bfr;
        #pragma unroll
        for (int j = 0; j < 8; j++) bfr.u[j] = f2bf(ew[j]);
        f32x4 acc[5] = {};
        #pragma unroll
        for (int ot = 0; ot < 5; ot++)
            acc[ot] = __builtin_amdgcn_mfma_f32_16x16x32_bf16(af[ot].b, bfr.b, acc[ot], 0, 0, 0);
        #pragma unroll
        for (int ot = 0; ot < 5; ot++) {
            union { unsigned short s[4]; uint2 v; } pk;
            #pragma unroll
            for (int r = 0; r < 4; r++) pk.s[r] = f2bf(eluf(acc[ot][r] + bf4[ot][r]));
            *(uint2*)&pt[t][cc * 80 + ot * 16 + 4 * lg] = pk.v;
        }
    }
    __syncthreads();
    const size_t base = ((size_t)b * KBN + 5 * (size_t)cp) * 3072;
    int q = 2 * tid;
    int l = q >> 3, jj = q & 7;
    int prow_lo = l & 15;
    int pcol_off = ((l >> 4) << 3) + jj;
    #pragma unroll
    for (int r = 0; r < 30; r++) {
        int kbl = r / 6, tt2 = r % 6;
        unsigned v = *(const unsigned*)&pt[tt2 * 16 + prow_lo][kbl * 32 + pcol_off];
        *(unsigned*)(p2 + base + (size_t)(kbl * 6 + tt2) * 512 + q) = v;
    }
}

// ---------------- conv2 pure MFMA GEMM over P2 (coalesced B) ----------------
__global__ __launch_bounds__(384) void k_conv2(const unsigned short* __restrict__ p2,
                                               const unsigned short* __restrict__ w2p,
                                               float* __restrict__ part) {
    int chunk = blockIdx.x, b = blockIdx.y;
    int tid = threadIdx.x, w = tid >> 6, l = tid & 63, lr = l & 15, lg = l >> 4;
    int kb0 = (chunk * KBN) / KSPLIT;
    int kb1 = ((chunk + 1) * KBN) / KSPLIT;
    const unsigned short* Bp = p2 + (size_t)b * KBN * 3072 + (size_t)w * 512 + (size_t)l * 8;
    const unsigned short* Arow = w2p + (size_t)lr * KP + 8 * lg;
    f32x4 acc[5] = {};
    for (int kb = kb0; kb < kb1; kb++) {
        BF8 bf; bf.u = *(const u16x8*)(Bp + (size_t)kb * 3072);
        int ko = kb * 32;
        #pragma unroll
        for (int mt = 0; mt < 5; mt++) {
            BF8 af; af.u = *(const u16x8*)(Arow + (size_t)mt * 16 * KP + ko);
            acc[mt] = __builtin_amdgcn_mfma_f32_16x16x32_bf16(af.b, bf.b, acc[mt], 0, 0, 0);
        }
    }
    float* pp = part + ((size_t)(chunk * BB + b) * WID) * TP;
    int t = w * 16 + lr;
    #pragma unroll
    for (int mt = 0; mt < 5; mt++) {
        int ob = mt * 16 + 4 * lg;
        #pragma unroll
        for (int r = 0; r < 4; r++)
            pp[(size_t)(ob + r) * TP + t] = acc[mt][r];
    }
}

// ---------------- reduce split-K + bn2 + elu + proj -> z_bf, split by t-quarter ----
// grid (4, 32): block (tq, b) reduces the 80x24 slice t in [tq*24, tq*24+24),
// then computes proj for its 24 t's. Same summation orders as the 32-block
// version -> bit-identical output; 4x the parallelism.
__global__ __launch_bounds__(256) void k_redproj(const float* __restrict__ part,
                                                 const float* __restrict__ scale2,
                                                 const float* __restrict__ shift2f,
                                                 const float* __restrict__ pw,
                                                 const float* __restrict__ pb,
                                                 unsigned short* __restrict__ zbf) {
    __shared__ float ly[WID * 24];   // 1920
    __shared__ float lw[EMB * WID];  // 640
    int tq = blockIdx.x, b = blockIdx.y;
    int tid = threadIdx.x;
    int t0 = tq * 24;
    for (int i = tid; i < EMB * WID; i += 256) lw[i] = pw[i];
    for (int i = tid; i < WID * 24; i += 256) {
        int o = i / 24, tl = i % 24;
        float acc = 0.f;
        #pragma unroll
        for (int ks = 0; ks < KSPLIT; ks++)
            acc += part[(size_t)(ks * BB + b) * (WID * TP) + o * TP + t0 + tl];
        ly[o * 24 + tl] = eluf(acc * scale2[o] + shift2f[o]);
    }
    __syncthreads();
    if (tid < 24 * EMB) {
        int e = tid & 7, tl = tid >> 3;
        float acc = pb[e];
        #pragma unroll 10
        for (int o = 0; o < WID; o++) acc = fmaf(ly[o * 24 + tl], lw[e * WID + o], acc);
        zbf[(size_t)b * HID + (t0 + tl) * EMB + e] = f2bf(acc);
    }
}

// ---------------- mlp1: 64 blocks x 16 cols; 4 waves = 2 batch-halves x 2 K-halves ----
__global__ __launch_bounds__(256) void k_mlp1(const unsigned short* __restrict__ zbf,
                                              const unsigned short* __restrict__ w1b,
                                              const float* __restrict__ bias,
                                              float* __restrict__ z1,
                                              unsigned short* __restrict__ gbf) {
    __shared__ float accb[2][64][4];
    int tid = threadIdx.x, w = tid >> 6, l = tid & 63, lr = l & 15, lg = l >> 4;
    int mt = w & 1, kh = w >> 1;
    int pcol = blockIdx.x * 16 + lr;
    const unsigned short* wr = w1b + (size_t)pcol * HID + kh * 384 + 8 * lg;
    const unsigned short* za = zbf + (size_t)(mt * 16 + lr) * HID + kh * 384 + 8 * lg;
    f32x4 acc = {};
    for (int kb = 0; kb < 384; kb += 32) {
        BF8 bf; bf.u = *(const u16x8*)(wr + kb);
        BF8 a;  a.u  = *(const u16x8*)(za + kb);
        acc = __builtin_amdgcn_mfma_f32_16x16x32_bf16(a.b, bf.b, acc, 0, 0, 0);
    }
    if (kh == 1) {
        #pragma unroll
        for (int r = 0; r < 4; r++) accb[mt][l][r] = acc[r];
    }
    __syncthreads();
    if (kh == 0) {
        float bs = bias[pcol];
        #pragma unroll
        for (int r = 0; r < 4; r++) {
            int row = mt * 16 + 4 * lg + r;
            float v = acc[r] + accb[mt][l][r] + bs;
            z1[(size_t)row * PROJ + pcol] = v;
            gbf[(size_t)row * PROJ + pcol] = f2bf(0.5f * v * (1.f + erff(v * 0.70710678118654752f)));
        }
    }
}

// ---------------- mlp2: 64 blocks x 16 cols; y = z1 + Gbf @ W2b^T + b2 ----------------
__global__ __launch_bounds__(256) void k_mlp2(const unsigned short* __restrict__ gbf,
                                              const float* __restrict__ z1,
                                              const unsigned short* __restrict__ w2b,
                                              const float* __restrict__ bias,
                                              float* __restrict__ y) {
    __shared__ float accb[2][64][4];
    int tid = threadIdx.x, w = tid >> 6, l = tid & 63, lr = l & 15, lg = l >> 4;
    int mt = w & 1, kh = w >> 1;
    int q = blockIdx.x * 16 + lr;
    const unsigned short* wr = w2b + (size_t)q * PROJ + kh * 512 + 8 * lg;
    const unsigned short* ga = gbf + (size_t)(mt * 16 + lr) * PROJ + kh * 512 + 8 * lg;
    f32x4 acc = {};
    for (int kb = 0; kb < 512; kb += 32) {
        BF8 bf; bf.u = *(const u16x8*)(wr + kb);
        BF8 a;  a.u  = *(const u16x8*)(ga + kb);
        acc = __builtin_amdgcn_mfma_f32_16x16x32_bf16(a.b, bf.b, acc, 0, 0, 0);
    }
    if (kh == 1) {
        #pragma unroll
        for (int r = 0; r < 4; r++) accb[mt][l][r] = acc[r];
    }
    __syncthreads();
    if (kh == 0) {
        float bs = bias[q];
        #pragma unroll
        for (int r = 0; r < 4; r++) {
            int row = mt * 16 + 4 * lg + r;
            y[(size_t)row * PROJ + q] = acc[r] + accb[mt][l][r] + bs + z1[(size_t)row * PROJ + q];
        }
    }
}

// ---------------- LayerNorm over 1024 per row -> d_out
__global__ __launch_bounds__(256) void k_ln(const float* __restrict__ y,
                                            const float* __restrict__ lg,
                                            const float* __restrict__ lb,
                                            float* __restrict__ out) {
    int b = blockIdx.x, tid = threadIdx.x;
    const float4* yr = (const float4*)(y + (size_t)b * PROJ);
    float4 v = yr[tid];
    float s  = v.x + v.y + v.z + v.w;
    float sq = v.x*v.x + v.y*v.y + v.z*v.z + v.w*v.w;
    #pragma unroll
    for (int off = 32; off > 0; off >>= 1) {
        s  += __shfl_down(s, off);
        sq += __shfl_down(sq, off);
    }
    __shared__ float ss[4], ssq[4];
    int wv = tid >> 6, lane = tid & 63;
    if (lane == 0) { ss[wv] = s; ssq[wv] = sq; }
    __syncthreads();
    __shared__ float smu, sinv;
    if (tid == 0) {
        float Sm = ss[0] + ss[1] + ss[2] + ss[3];
        float Sq = ssq[0] + ssq[1] + ssq[2] + ssq[3];
        float mu = Sm * (1.f / PROJ);
        float var = Sq * (1.f / PROJ) - mu * mu;
        smu = mu;
        sinv = rsqrtf(var + EPSF);
    }
    __syncthreads();
    float mu = smu, inv = sinv;
    float4 g4 = ((const float4*)lg)[tid];
    float4 b4 = ((const float4*)lb)[tid];
    float4 o4;
    o4.x = (v.x - mu) * inv * g4.x + b4.x;
    o4.y = (v.y - mu) * inv * g4.y + b4.y;
    o4.z = (v.z - mu) * inv * g4.z + b4.z;
    o4.w = (v.w - mu) * inv * g4.w + b4.w;
    ((float4*)(out + (size_t)b * PROJ))[tid] = o4;
}

extern "C" void kernel_launch(void* const* d_in, const int* in_sizes, int n_in,
                              void* d_out, int out_size, void* d_ws, size_t ws_size,
                              hipStream_t stream) {
    const float* x        = (const float*)d_in[0];
    const int*   sid      = (const int*)  d_in[1];
    const float* W_sub    = (const float*)d_in[2];
    const float* b_sub    = (const float*)d_in[3];
    const float* conv1_w  = (const float*)d_in[4];
    const float* conv1_b  = (const float*)d_in[5];
    const float* bn1_g    = (const float*)d_in[6];
    const float* bn1_b    = (const float*)d_in[7];
    const float* bn1_m    = (const float*)d_in[8];
    const float* bn1_v    = (const float*)d_in[9];
    const float* conv2_w  = (const float*)d_in[10];
    const float* conv2_b  = (const float*)d_in[11];
    const float* bn2_g    = (const float*)d_in[12];
    const float* bn2_b    = (const float*)d_in[13];
    const float* bn2_m    = (const float*)d_in[14];
    const float* bn2_v    = (const float*)d_in[15];
    const float* proj_w   = (const float*)d_in[16];
    const float* proj_b   = (const float*)d_in[17];
    const float* mlp1_w   = (const float*)d_in[18];
    const float* mlp1_b   = (const float*)d_in[19];
    const float* mlp2_w   = (const float*)d_in[20];
    const float* mlp2_b   = (const float*)d_in[21];
    const float* ln_g     = (const float*)d_in[22];
    const float* ln_b     = (const float*)d_in[23];
    float* out = (float*)d_out;
    float* ws  = (float*)d_ws;

    float* ws_e    = ws + OFF_E;
    unsigned short* ws_xb  = (unsigned short*)(ws + OFF_XB);
    unsigned short* ws_wb  = (unsigned short*)(ws + OFF_WB);
    unsigned short* ws_w2p = (unsigned short*)(ws + OFF_W2P);
    unsigned short* ws_p2  = (unsigned short*)(ws + OFF_P);
    float* ws_part = ws + OFF_PART;
    unsigned short* ws_zbf = (unsigned short*)(ws + OFF_Z);
    float* ws_z1   = ws + OFF_Z1;
    unsigned short* ws_gbf = (unsigned short*)(ws + OFF_G);
    float* ws_y    = ws + OFF_Y;
    unsigned short* ws_w1b = (unsigned short*)(ws + OFF_W1B);
    unsigned short* ws_w2b = (unsigned short*)(ws + OFF_W2B);
    unsigned short* ws_wcb = (unsigned short*)(ws + OFF_WCB);
    float* ws_b1f  = ws + OFF_B1F;
    float* ws_sc2  = ws + OFF_SC2;
    float* ws_sh2  = ws + OFF_SH2;

    hipLaunchKernelGGL(k_pack, dim3((NPK_TOT + 255) / 256), dim3(256), 0, stream,
                       x, W_sub, conv2_w, mlp1_w, mlp2_w,
                       conv1_w, conv1_b, bn1_g, bn1_b, bn1_m, bn1_v,
                       conv2_b, bn2_g, bn2_b, bn2_m, bn2_v,
                       ws_xb, ws_wb, ws_w2p, ws_w1b, ws_w2b,
                       ws_wcb, ws_b1f, ws_sc2, ws_sh2);

    hipLaunchKernelGGL(k_einsum, dim3(8, BB), dim3(256), 0, stream,
                       ws_xb, ws_wb, sid, b_sub, ws_e);

    hipLaunchKernelGGL(k_fir2, dim3(CC / 2, BB), dim3(256), 0, stream,
                       ws_e, ws_wcb, ws_b1f, ws_p2);

    hipLaunchKernelGGL(k_conv2, dim3(KSPLIT, BB), dim3(384), 0, stream,
                       ws_p2, ws_w2p, ws_part);

    hipLaunchKernelGGL(k_redproj, dim3(4, BB), dim3(256), 0, stream,
                       ws_part, ws_sc2, ws_sh2, proj_w, proj_b, ws_zbf);

    hipLaunchKernelGGL(k_mlp1, dim3(PROJ / 16), dim3(256), 0, stream,
                       ws_zbf, ws_w1b, mlp1_b, ws_z1, ws_gbf);

    hipLaunchKernelGGL(k_mlp2, dim3(PROJ / 16), dim3(256), 0, stream,
                       ws_gbf, ws_z1, ws_w2b, mlp2_b, ws_y);

    hipLaunchKernelGGL(k_ln, dim3(BB), dim3(256), 0, stream,
                       ws_y, ln_g, ln_b, out);
}

// Round 15
// 201.620 us; speedup vs baseline: 1.2255x; 1.0631x over previous
//
#include <hip/hip_runtime.h>
#include <math.h>

// Problem constants
#define BB 32
#define CC 122
#define TT 500
#define SS 13
#define WID 80
#define EMB 8
#define PROJ 1024
#define HID 768
#define TP 96          // pooled time length
#define EPSF 1e-5f
#define KP 9760        // conv2 flat K' = 122*80
#define KSPLIT 16      // 16 chunks x 4 c-pairs (c-pairs 61..63 are zero/skip)

typedef float f32x4 __attribute__((ext_vector_type(4)));
typedef __bf16 bf16x8 __attribute__((ext_vector_type(8)));
typedef unsigned short u16x8 __attribute__((ext_vector_type(8)));
union BF8 { u16x8 u; bf16x8 b; };

// float -> bf16 bits, round-to-nearest-even
__device__ __forceinline__ unsigned short f2bf(float f) {
    union { float f; unsigned u; } v; v.f = f;
    unsigned r = v.u + 0x7FFFu + ((v.u >> 16) & 1u);
    return (unsigned short)(r >> 16);
}

// cheap ELU: hw v_exp; |err| ~1e-7, invisible vs bf16 noise
__device__ __forceinline__ float eluf(float x) {
    return x > 0.f ? x : __expf(x) - 1.f;
}

// ---------------- workspace layout (float offsets) ----------------
#define OFF_E    ((size_t)0)            // oute (B,C,T) f32        1,952,000
#define OFF_XB   ((size_t)1952000)      // x_bf (B,128,512) bf16
#define OFF_WB   ((size_t)3000576)      // W_bf (S,512,512) bf16
#define OFF_W2P  ((size_t)4704512)      // w2p (80,9760) bf16
#define OFF_PART ((size_t)20086272)     // (KS,B,WID,TP) f32
#define OFF_Z    ((size_t)24018432)     // z_bf (B,HID) bf16
#define OFF_Z1   ((size_t)24030720)     // z1 (B,PROJ) f32
#define OFF_G    ((size_t)24063488)     // g_bf (B,PROJ) bf16
#define OFF_Y    ((size_t)24079872)     // y (B,PROJ) f32
#define OFF_W1B  ((size_t)24112640)     // w1b (PROJ,HID) bf16
#define OFF_W2B  ((size_t)24505856)     // w2b (PROJ,PROJ) bf16
#define OFF_WCB  ((size_t)25030144)     // wcb (80,32) bf16
#define OFF_B1F  ((size_t)25031424)     // (WID)
#define OFF_SC2  ((size_t)25031504)     // (WID)
#define OFF_SH2  ((size_t)25031584)     // (WID)

// pack region sizes (elements)
#define NPK_X  (2097152)   // 32*128*512
#define NPK_W  (3407872)   // 13*512*512
#define NPK_W2 (780800)    // 80*9760
#define NPK_M1 (786432)    // 1024*768
#define NPK_M2 (1048576)   // 1024*1024
#define NPK_TOT (NPK_X + NPK_W + NPK_W2 + NPK_M1 + NPK_M2)

// ---------------- pack (bf16 staging) + prep (block 0) ----------------
__global__ __launch_bounds__(256) void k_pack(const float* __restrict__ x,
                                              const float* __restrict__ W_sub,
                                              const float* __restrict__ conv2_w,
                                              const float* __restrict__ mlp1_w,
                                              const float* __restrict__ mlp2_w,
                                              const float* __restrict__ conv1_w, const float* __restrict__ conv1_b,
                                              const float* __restrict__ g1, const float* __restrict__ b1,
                                              const float* __restrict__ m1, const float* __restrict__ v1,
                                              const float* __restrict__ conv2_b, const float* __restrict__ g2,
                                              const float* __restrict__ b2, const float* __restrict__ m2,
                                              const float* __restrict__ v2,
                                              unsigned short* __restrict__ xb,
                                              unsigned short* __restrict__ wb,
                                              unsigned short* __restrict__ w2p,
                                              unsigned short* __restrict__ w1b,
                                              unsigned short* __restrict__ w2b,
                                              unsigned short* __restrict__ wcb, float* __restrict__ bias1f,
                                              float* __restrict__ scale2, float* __restrict__ shift2f) {
    if (blockIdx.x == 0) {
        int o = threadIdx.x;
        if (o < WID) {
            float s1 = g1[o] * rsqrtf(v1[o] + EPSF);
            float sh1 = b1[o] - m1[o] * s1;
            #pragma unroll
            for (int d = 0; d < 21; d++) {
                int klo = d - 16; if (klo < 0) klo = 0;
                int khi = d;      if (khi > 4) khi = 4;
                float acc = 0.f;
                for (int k = klo; k <= khi; k++) acc += conv1_w[o*5 + k];
                wcb[o*32 + d] = f2bf(acc * s1 * (1.f/17.f));
            }
            #pragma unroll
            for (int d = 21; d < 32; d++) wcb[o*32 + d] = 0;
            bias1f[o] = conv1_b[o] * s1 + sh1;
            float s2 = g2[o] * rsqrtf(v2[o] + EPSF);
            scale2[o] = s2;
            shift2f[o] = conv2_b[o] * s2 + (b2[o] - m2[o] * s2);
        }
    }
    size_t idx = (size_t)blockIdx.x * 256 + threadIdx.x;
    if (idx >= (size_t)NPK_TOT) return;
    if (idx < NPK_X) {
        int s = idx & 511, c = (idx >> 9) & 127, b = idx >> 16;
        float v = (c < CC && s < TT) ? x[((size_t)b * CC + c) * TT + s] : 0.f;
        xb[idx] = f2bf(v);
    } else if (idx < NPK_X + NPK_W) {
        size_t j = idx - NPK_X;
        int s = j & 511, t = (j >> 9) & 511, sub = j >> 18;
        float v = (t < TT && s < TT) ? W_sub[((size_t)sub * TT + t) * TT + s] : 0.f;
        wb[j] = f2bf(v);
    } else if (idx < NPK_X + NPK_W + NPK_W2) {
        // coalesced READ of conv2_w (c fastest = native order); scattered 2B
        // write absorbed by L2 write-back.
        size_t j = idx - NPK_X - NPK_W;
        int o  = (int)(j / (WID * CC));
        int r  = (int)(j % (WID * CC));
        int op = r / CC, c = r % CC;
        w2p[(size_t)o * KP + (size_t)c * WID + op] = f2bf(conv2_w[j]);
    } else if (idx < NPK_X + NPK_W + NPK_W2 + NPK_M1) {
        size_t j = idx - NPK_X - NPK_W - NPK_W2;
        w1b[j] = f2bf(mlp1_w[j]);
    } else {
        size_t j = idx - NPK_X - NPK_W - NPK_W2 - NPK_M1;
        w2b[j] = f2bf(mlp2_w[j]);
    }
}

// ---------------- subject einsum via MFMA bf16 ----------------
__global__ __launch_bounds__(256) void k_einsum(const unsigned short* __restrict__ xb,
                                                const unsigned short* __restrict__ wb,
                                                const int* __restrict__ sid,
                                                const float* __restrict__ b_sub,
                                                float* __restrict__ oute) {
    int t0 = blockIdx.x * 64, b = blockIdx.y;
    int s = sid[b];
    int tid = threadIdx.x, w = tid >> 6, lr = tid & 15, lg = (tid >> 4) & 3;
    const unsigned short* A0 = xb + ((size_t)(b * 128 + w * 32 + lr)) * 512 + 8 * lg;
    const unsigned short* Bb = wb + (size_t)s * 262144 + 8 * lg;
    f32x4 acc[2][4] = {};
    for (int kb = 0; kb < 512; kb += 32) {
        BF8 a0, a1;
        a0.u = *(const u16x8*)(A0 + kb);
        a1.u = *(const u16x8*)(A0 + 16 * 512 + kb);
        #pragma unroll
        for (int nt = 0; nt < 4; nt++) {
            BF8 bf; bf.u = *(const u16x8*)(Bb + (size_t)(t0 + nt * 16 + lr) * 512 + kb);
            acc[0][nt] = __builtin_amdgcn_mfma_f32_16x16x32_bf16(a0.b, bf.b, acc[0][nt], 0, 0, 0);
            acc[1][nt] = __builtin_amdgcn_mfma_f32_16x16x32_bf16(a1.b, bf.b, acc[1][nt], 0, 0, 0);
        }
    }
    const float* bg = b_sub + (size_t)s * TT;
    #pragma unroll
    for (int nt = 0; nt < 4; nt++) {
        int t = t0 + nt * 16 + lr;
        if (t < TT) {
            float bias = bg[t];
            #pragma unroll
            for (int mt = 0; mt < 2; mt++) {
                int crow = w * 32 + mt * 16 + 4 * lg;
                #pragma unroll
                for (int r = 0; r < 4; r++) {
                    int c = crow + r;
                    if (c < CC) oute[((size_t)b * CC + c) * TT + t] = acc[mt][nt][r] + bias;
                }
            }
        }
    }
}

// ---------------- fused FIR+conv2: p never touches HBM ----------------
// grid (16 chunks, 32 b) x 384 thr (6 waves). Chunk = c-pairs [4*chunk, 4*chunk+4),
// cp>=61 skipped (zero contribution). Per c-pair: e rows -> LDS; FIR via MFMA
// (wave w covers units (cc=0,tt=w),(cc=1,tt=w)) -> pt[96][164] bf16 in LDS;
// conv MFMA (wave=tt, 5 kl x 5 mt) accumulates across all 4 c-pairs.
// part[chunk][b][o][t] written once at the end.
__global__ __launch_bounds__(384) void k_fc(const float* __restrict__ oute,
                                            const unsigned short* __restrict__ wcb,
                                            const float* __restrict__ b1f,
                                            const unsigned short* __restrict__ w2p,
                                            float* __restrict__ part) {
    __shared__ float e2[2][512];
    __shared__ unsigned short pt[96][164];   // stride 164: store pattern conflict-free
    int chunk = blockIdx.x, b = blockIdx.y;
    int tid = threadIdx.x, w = tid >> 6, l = tid & 63, lr = l & 15, lg = l >> 4;
    // FIR constants (preload; identical across c-pairs)
    BF8 af[5]; float4 bf4[5];
    #pragma unroll
    for (int ot = 0; ot < 5; ot++) {
        af[ot].u = *(const u16x8*)(wcb + (ot * 16 + lr) * 32 + 8 * lg);
        bf4[ot] = *(const float4*)(b1f + ot * 16 + 4 * lg);
    }
    const unsigned short* Arow = w2p + (size_t)lr * KP + 8 * lg;
    f32x4 acc2[5] = {};
    for (int ci = 0; ci < 4; ci++) {
        int cp = chunk * 4 + ci;
        bool live = cp < 61;              // block-uniform
        if (live) {
            if (tid < 250) {
                int cc = tid / 125, i = tid % 125;
                ((float4*)e2[cc])[i] = ((const float4*)(oute + ((size_t)b * CC + cp * 2 + cc) * TT))[i];
            }
            if (tid >= 232 && tid < 256) {   // zero-pad e[500..511] both rows
                int j = tid - 232; int cc = j / 12, i = 500 + (j % 12);
                e2[cc][i] = 0.f;
            }
        }
        __syncthreads();                  // e2 ready; prev-iter pt reads done
        if (live) {
            #pragma unroll
            for (int cc = 0; cc < 2; cc++) {
                int t = w * 16 + lr;
                const float* ew = e2[cc] + 5 * t + 8 * lg;
                BF8 bfr;
                #pragma unroll
                for (int j = 0; j < 8; j++) bfr.u[j] = f2bf(ew[j]);
                f32x4 fa[5] = {};
                #pragma unroll
                for (int ot = 0; ot < 5; ot++)
                    fa[ot] = __builtin_amdgcn_mfma_f32_16x16x32_bf16(af[ot].b, bfr.b, fa[ot], 0, 0, 0);
                #pragma unroll
                for (int ot = 0; ot < 5; ot++) {
                    union { unsigned short s[4]; uint2 v; } pk;
                    #pragma unroll
                    for (int r = 0; r < 4; r++) pk.s[r] = f2bf(eluf(fa[ot][r] + bf4[ot][r]));
                    *(uint2*)&pt[t][cc * 80 + ot * 16 + 4 * lg] = pk.v;
                }
            }
        }
        __syncthreads();                  // pt ready
        if (live) {
            #pragma unroll
            for (int kl = 0; kl < 5; kl++) {
                BF8 bf; bf.u = *(const u16x8*)(&pt[w * 16 + lr][kl * 32 + lg * 8]);
                int ko = cp * 160 + kl * 32;
                #pragma unroll
                for (int mt = 0; mt < 5; mt++) {
                    BF8 a; a.u = *(const u16x8*)(Arow + (size_t)mt * 16 * KP + ko);
                    acc2[mt] = __builtin_amdgcn_mfma_f32_16x16x32_bf16(a.b, bf.b, acc2[mt], 0, 0, 0);
                }
            }
        }
    }
    float* pp = part + ((size_t)(chunk * BB + b) * WID) * TP;
    int t = w * 16 + lr;
    #pragma unroll
    for (int mt = 0; mt < 5; mt++) {
        int ob = mt * 16 + 4 * lg;
        #pragma unroll
        for (int r = 0; r < 4; r++)
            pp[(size_t)(ob + r) * TP + t] = acc2[mt][r];
    }
}

// ---------------- reduce split-K + bn2 + elu + proj -> z_bf, split by t-quarter ----
__global__ __launch_bounds__(256) void k_redproj(const float* __restrict__ part,
                                                 const float* __restrict__ scale2,
                                                 const float* __restrict__ shift2f,
                                                 const float* __restrict__ pw,
                                                 const float* __restrict__ pb,
                                                 unsigned short* __restrict__ zbf) {
    __shared__ float ly[WID * 24];   // 1920
    __shared__ float lw[EMB * WID];  // 640
    int tq = blockIdx.x, b = blockIdx.y;
    int tid = threadIdx.x;
    int t0 = tq * 24;
    for (int i = tid; i < EMB * WID; i += 256) lw[i] = pw[i];
    for (int i = tid; i < WID * 24; i += 256) {
        int o = i / 24, tl = i % 24;
        float acc = 0.f;
        #pragma unroll
        for (int ks = 0; ks < KSPLIT; ks++)
            acc += part[(size_t)(ks * BB + b) * (WID * TP) + o * TP + t0 + tl];
        ly[o * 24 + tl] = eluf(acc * scale2[o] + shift2f[o]);
    }
    __syncthreads();
    if (tid < 24 * EMB) {
        int e = tid & 7, tl = tid >> 3;
        float acc = pb[e];
        #pragma unroll 10
        for (int o = 0; o < WID; o++) acc = fmaf(ly[o * 24 + tl], lw[e * WID + o], acc);
        zbf[(size_t)b * HID + (t0 + tl) * EMB + e] = f2bf(acc);
    }
}

// ---------------- mlp1: 64 blocks x 16 cols; 4 waves = 2 batch-halves x 2 K-halves ----
__global__ __launch_bounds__(256) void k_mlp1(const unsigned short* __restrict__ zbf,
                                              const unsigned short* __restrict__ w1b,
                                              const float* __restrict__ bias,
                                              float* __restrict__ z1,
                                              unsigned short* __restrict__ gbf) {
    __shared__ float accb[2][64][4];
    int tid = threadIdx.x, w = tid >> 6, l = tid & 63, lr = l & 15, lg = l >> 4;
    int mt = w & 1, kh = w >> 1;
    int pcol = blockIdx.x * 16 + lr;
    const unsigned short* wr = w1b + (size_t)pcol * HID + kh * 384 + 8 * lg;
    const unsigned short* za = zbf + (size_t)(mt * 16 + lr) * HID + kh * 384 + 8 * lg;
    f32x4 acc = {};
    for (int kb = 0; kb < 384; kb += 32) {
        BF8 bf; bf.u = *(const u16x8*)(wr + kb);
        BF8 a;  a.u  = *(const u16x8*)(za + kb);
        acc = __builtin_amdgcn_mfma_f32_16x16x32_bf16(a.b, bf.b, acc, 0, 0, 0);
    }
    if (kh == 1) {
        #pragma unroll
        for (int r = 0; r < 4; r++) accb[mt][l][r] = acc[r];
    }
    __syncthreads();
    if (kh == 0) {
        float bs = bias[pcol];
        #pragma unroll
        for (int r = 0; r < 4; r++) {
            int row = mt * 16 + 4 * lg + r;
            float v = acc[r] + accb[mt][l][r] + bs;
            z1[(size_t)row * PROJ + pcol] = v;
            gbf[(size_t)row * PROJ + pcol] = f2bf(0.5f * v * (1.f + erff(v * 0.70710678118654752f)));
        }
    }
}

// ---------------- mlp2: 64 blocks x 16 cols; y = z1 + Gbf @ W2b^T + b2 ----------------
__global__ __launch_bounds__(256) void k_mlp2(const unsigned short* __restrict__ gbf,
                                              const float* __restrict__ z1,
                                              const unsigned short* __restrict__ w2b,
                                              const float* __restrict__ bias,
                                              float* __restrict__ y) {
    __shared__ float accb[2][64][4];
    int tid = threadIdx.x, w = tid >> 6, l = tid & 63, lr = l & 15, lg = l >> 4;
    int mt = w & 1, kh = w >> 1;
    int q = blockIdx.x * 16 + lr;
    const unsigned short* wr = w2b + (size_t)q * PROJ + kh * 512 + 8 * lg;
    const unsigned short* ga = gbf + (size_t)(mt * 16 + lr) * PROJ + kh * 512 + 8 * lg;
    f32x4 acc = {};
    for (int kb = 0; kb < 512; kb += 32) {
        BF8 bf; bf.u = *(const u16x8*)(wr + kb);
        BF8 a;  a.u  = *(const u16x8*)(ga + kb);
        acc = __builtin_amdgcn_mfma_f32_16x16x32_bf16(a.b, bf.b, acc, 0, 0, 0);
    }
    if (kh == 1) {
        #pragma unroll
        for (int r = 0; r < 4; r++) accb[mt][l][r] = acc[r];
    }
    __syncthreads();
    if (kh == 0) {
        float bs = bias[q];
        #pragma unroll
        for (int r = 0; r < 4; r++) {
            int row = mt * 16 + 4 * lg + r;
            y[(size_t)row * PROJ + q] = acc[r] + accb[mt][l][r] + bs + z1[(size_t)row * PROJ + q];
        }
    }
}

// ---------------- LayerNorm over 1024 per row -> d_out
__global__ __launch_bounds__(256) void k_ln(const float* __restrict__ y,
                                            const float* __restrict__ lg,
                                            const float* __restrict__ lb,
                                            float* __restrict__ out) {
    int b = blockIdx.x, tid = threadIdx.x;
    const float4* yr = (const float4*)(y + (size_t)b * PROJ);
    float4 v = yr[tid];
    float s  = v.x + v.y + v.z + v.w;
    float sq = v.x*v.x + v.y*v.y + v.z*v.z + v.w*v.w;
    #pragma unroll
    for (int off = 32; off > 0; off >>= 1) {
        s  += __shfl_down(s, off);
        sq += __shfl_down(sq, off);
    }
    __shared__ float ss[4], ssq[4];
    int wv = tid >> 6, lane = tid & 63;
    if (lane == 0) { ss[wv] = s; ssq[wv] = sq; }
    __syncthreads();
    __shared__ float smu, sinv;
    if (tid == 0) {
        float Sm = ss[0] + ss[1] + ss[2] + ss[3];
        float Sq = ssq[0] + ssq[1] + ssq[2] + ssq[3];
        float mu = Sm * (1.f / PROJ);
        float var = Sq * (1.f / PROJ) - mu * mu;
        smu = mu;
        sinv = rsqrtf(var + EPSF);
    }
    __syncthreads();
    float mu = smu, inv = sinv;
    float4 g4 = ((const float4*)lg)[tid];
    float4 b4 = ((const float4*)lb)[tid];
    float4 o4;
    o4.x = (v.x - mu) * inv * g4.x + b4.x;
    o4.y = (v.y - mu) * inv * g4.y + b4.y;
    o4.z = (v.z - mu) * inv * g4.z + b4.z;
    o4.w = (v.w - mu) * inv * g4.w + b4.w;
    ((float4*)(out + (size_t)b * PROJ))[tid] = o4;
}

extern "C" void kernel_launch(void* const* d_in, const int* in_sizes, int n_in,
                              void* d_out, int out_size, void* d_ws, size_t ws_size,
                              hipStream_t stream) {
    const float* x        = (const float*)d_in[0];
    const int*   sid      = (const int*)  d_in[1];
    const float* W_sub    = (const float*)d_in[2];
    const float* b_sub    = (const float*)d_in[3];
    const float* conv1_w  = (const float*)d_in[4];
    const float* conv1_b  = (const float*)d_in[5];
    const float* bn1_g    = (const float*)d_in[6];
    const float* bn1_b    = (const float*)d_in[7];
    const float* bn1_m    = (const float*)d_in[8];
    const float* bn1_v    = (const float*)d_in[9];
    const float* conv2_w  = (const float*)d_in[10];
    const float* conv2_b  = (const float*)d_in[11];
    const float* bn2_g    = (const float*)d_in[12];
    const float* bn2_b    = (const float*)d_in[13];
    const float* bn2_m    = (const float*)d_in[14];
    const float* bn2_v    = (const float*)d_in[15];
    const float* proj_w   = (const float*)d_in[16];
    const float* proj_b   = (const float*)d_in[17];
    const float* mlp1_w   = (const float*)d_in[18];
    const float* mlp1_b   = (const float*)d_in[19];
    const float* mlp2_w   = (const float*)d_in[20];
    const float* mlp2_b   = (const float*)d_in[21];
    const float* ln_g     = (const float*)d_in[22];
    const float* ln_b     = (const float*)d_in[23];
    float* out = (float*)d_out;
    float* ws  = (float*)d_ws;

    float* ws_e    = ws + OFF_E;
    unsigned short* ws_xb  = (unsigned short*)(ws + OFF_XB);
    unsigned short* ws_wb  = (unsigned short*)(ws + OFF_WB);
    unsigned short* ws_w2p = (unsigned short*)(ws + OFF_W2P);
    float* ws_part = ws + OFF_PART;
    unsigned short* ws_zbf = (unsigned short*)(ws + OFF_Z);
    float* ws_z1   = ws + OFF_Z1;
    unsigned short* ws_gbf = (unsigned short*)(ws + OFF_G);
    float* ws_y    = ws + OFF_Y;
    unsigned short* ws_w1b = (unsigned short*)(ws + OFF_W1B);
    unsigned short* ws_w2b = (unsigned short*)(ws + OFF_W2B);
    unsigned short* ws_wcb = (unsigned short*)(ws + OFF_WCB);
    float* ws_b1f  = ws + OFF_B1F;
    float* ws_sc2  = ws + OFF_SC2;
    float* ws_sh2  = ws + OFF_SH2;

    hipLaunchKernelGGL(k_pack, dim3((NPK_TOT + 255) / 256), dim3(256), 0, stream,
                       x, W_sub, conv2_w, mlp1_w, mlp2_w,
                       conv1_w, conv1_b, bn1_g, bn1_b, bn1_m, bn1_v,
                       conv2_b, bn2_g, bn2_b, bn2_m, bn2_v,
                       ws_xb, ws_wb, ws_w2p, ws_w1b, ws_w2b,
                       ws_wcb, ws_b1f, ws_sc2, ws_sh2);

    hipLaunchKernelGGL(k_einsum, dim3(8, BB), dim3(256), 0, stream,
                       ws_xb, ws_wb, sid, b_sub, ws_e);

    hipLaunchKernelGGL(k_fc, dim3(KSPLIT, BB), dim3(384), 0, stream,
                       ws_e, ws_wcb, ws_b1f, ws_w2p, ws_part);

    hipLaunchKernelGGL(k_redproj, dim3(4, BB), dim3(256), 0, stream,
                       ws_part, ws_sc2, ws_sh2, proj_w, proj_b, ws_zbf);

    hipLaunchKernelGGL(k_mlp1, dim3(PROJ / 16), dim3(256), 0, stream,
                       ws_zbf, ws_w1b, mlp1_b, ws_z1, ws_gbf);

    hipLaunchKernelGGL(k_mlp2, dim3(PROJ / 16), dim3(256), 0, stream,
                       ws_gbf, ws_z1, ws_w2b, mlp2_b, ws_y);

    hipLaunchKernelGGL(k_ln, dim3(BB), dim3(256), 0, stream,
                       ws_y, ln_g, ln_b, out);
}